// Round 1
// 612.732 us; speedup vs baseline: 1.1629x; 1.1629x over previous
//
#include <hip/hip_runtime.h>

// Capsule routing: B=64, R=2048, C=32, O=32, I=32, 3 iterations.
// Round 6: latency-bound fix. Split W-convert stream from MFMA work; halve
// per-wave tile (8 tiles, 32 acc regs) and double n-blocks -> ~50% occupancy.
// part shrunk to 32MB (RPB=16) + two-stage vectorized reduction.

#define B_  64
#define R_  2048
#define CI  32     // in channels (K)
#define NC  32     // num capsules
#define OC  32     // out channels
#define NCO 1024   // NC*OC, the N dimension
#define RPB 16     // routes per block
#define GR  (R_ / RPB)   // 128 blocks in r-dim
#define NG  8      // n-dim blocks (128 cols each)
#define NSL 128    // n columns per block
#define BN  65536  // B_*NCO elements of one partial slice

typedef __attribute__((ext_vector_type(8))) short bf16x8;
typedef __attribute__((ext_vector_type(4))) float f32x4;

static constexpr long WN = (long)R_ * NCO * CI;  // 67,108,864
static constexpr long XN = (long)B_ * R_ * CI;   // 4,194,304

__device__ __forceinline__ unsigned short rne_bf16(float f) {
  unsigned int u = __builtin_bit_cast(unsigned int, f);
  u += 0x7fffu + ((u >> 16) & 1u);   // round-to-nearest-even (finite inputs)
  return (unsigned short)(u >> 16);
}

__device__ __forceinline__ bf16x8 pack8(f32x4 a, f32x4 b) {
  bf16x8 r;
  r[0] = (short)rne_bf16(a[0]); r[1] = (short)rne_bf16(a[1]);
  r[2] = (short)rne_bf16(a[2]); r[3] = (short)rne_bf16(a[3]);
  r[4] = (short)rne_bf16(b[0]); r[5] = (short)rne_bf16(b[1]);
  r[6] = (short)rne_bf16(b[2]); r[7] = (short)rne_bf16(b[3]);
  return r;
}

// f32 -> bf16 for x (small)
__global__ __launch_bounds__(256) void cvt_kernel(const float* __restrict__ src,
                                                  unsigned short* __restrict__ dst,
                                                  int n4) {
  int i = blockIdx.x * blockDim.x + threadIdx.x;
  int stride = gridDim.x * blockDim.x;
  const f32x4* s4 = (const f32x4*)src;
  ushort4* d4 = (ushort4*)dst;
  for (; i < n4; i += stride) {
    f32x4 f = s4[i];
    ushort4 u;
    u.x = rne_bf16(f[0]); u.y = rne_bf16(f[1]);
    u.z = rne_bf16(f[2]); u.w = rne_bf16(f[3]);
    d4[i] = u;
  }
}

// Pure streaming W f32 -> bf16: nt-load the one-shot f32 stream, cacheable
// store of Wb (re-read 5x, want it in L3). 2048 blocks -> full occupancy.
__global__ __launch_bounds__(256) void cvtW_kernel(const float* __restrict__ src,
                                                   unsigned short* __restrict__ dst) {
  long i = (long)blockIdx.x * 256 + threadIdx.x;   // group of 8 floats
  const long stride = (long)gridDim.x * 256;
  const long n8 = WN / 8;
  const f32x4* s4 = (const f32x4*)src;
  bf16x8* d8 = (bf16x8*)dst;
  for (; i < n8; i += stride) {
    f32x4 a = __builtin_nontemporal_load(s4 + 2 * i);
    f32x4 b = __builtin_nontemporal_load(s4 + 2 * i + 1);
    d8[i] = pack8(a, b);
  }
}

// s-pass: part[rx][b][n] = sum_{r in block} c[r,cap(n)] * (W[r,n,:] . x[b,r,:])
// UNIFORM: c == 1/2048 folded into the store; MFMA accumulates in C directly.
// Wave tile: 16 b-rows x 128 n = 8 MFMA tiles -> 32 acc VGPRs.
template<bool FAST, bool UNIFORM>
__global__ __launch_bounds__(256, 4) void s_kernel(
    const float* __restrict__ x, const float* __restrict__ W,
    const unsigned short* __restrict__ xb, const unsigned short* __restrict__ Wb,
    const float* __restrict__ cmat,   // [C][R] (unused if UNIFORM)
    float* __restrict__ part) {       // [GR][B_][NCO]
  const int tid  = threadIdx.x;
  const int lane = tid & 63;
  const int mw   = tid >> 6;
  const int g    = blockIdx.y;
  const int r0   = blockIdx.x * RPB;
  const int l15  = lane & 15;
  const int q    = lane >> 4;
  const int k0   = q * 8;
  const int bA   = mw * 16 + l15;

  f32x4 acc[8];
#pragma unroll
  for (int t = 0; t < 8; ++t) acc[t] = (f32x4){0.f, 0.f, 0.f, 0.f};
  const f32x4 zero4 = (f32x4){0.f, 0.f, 0.f, 0.f};

  for (int j = 0; j < RPB; ++j) {
    const int r = r0 + j;
    bf16x8 af;
    if (FAST) {
      af = *(const bf16x8*)(xb + ((bA * R_ + r) * CI + k0));
    } else {
      const f32x4* xp = (const f32x4*)(x + ((bA * R_ + r) * CI + k0));
      af = pack8(xp[0], xp[1]);
    }
    bf16x8 wf[8];
#pragma unroll
    for (int t = 0; t < 8; ++t) {
      const int nrow = g * NSL + t * 16 + l15;
      const int wof = (r * NCO + nrow) * CI + k0;
      if (FAST) wf[t] = *(const bf16x8*)(Wb + wof);
      else {
        const f32x4* wp = (const f32x4*)(W + wof);
        wf[t] = pack8(wp[0], wp[1]);
      }
    }
    if (UNIFORM) {
#pragma unroll
      for (int t = 0; t < 8; ++t)
        acc[t] = __builtin_amdgcn_mfma_f32_16x16x32_bf16(af, wf[t], acc[t], 0, 0, 0);
    } else {
      float cv[4];
#pragma unroll
      for (int cc = 0; cc < 4; ++cc) cv[cc] = cmat[(g * 4 + cc) * R_ + r];
#pragma unroll
      for (int t = 0; t < 8; ++t) {
        f32x4 u = __builtin_amdgcn_mfma_f32_16x16x32_bf16(af, wf[t], zero4, 0, 0, 0);
        acc[t] += cv[t >> 1] * u;   // capsule constant over a 32-wide n pair
      }
    }
  }
  // C/D layout: row(m) = q*4 + rr, col(n) = l15
  const int pbase = blockIdx.x * BN;
#pragma unroll
  for (int t = 0; t < 8; ++t) {
    const int n = g * NSL + t * 16 + l15;
#pragma unroll
    for (int rr = 0; rr < 4; ++rr) {
      const int b = mw * 16 + q * 4 + rr;
      part[pbase + b * NCO + n] = UNIFORM ? acc[t][rr] * (1.0f / 2048.0f)
                                          : acc[t][rr];
    }
  }
}

// reduction stage 1: sum 16 of the GR=128 slices -> part2[8][B][NCO]
__global__ __launch_bounds__(256) void rs1_kernel(const float* __restrict__ part,
                                                  float* __restrict__ part2) {
  const int i4 = blockIdx.x * 256 + threadIdx.x;   // f32x4 index, BN/4=16384
  const int ip = blockIdx.y;
  const f32x4* p4 = (const f32x4*)part;
  f32x4 s = (f32x4){0.f, 0.f, 0.f, 0.f};
#pragma unroll
  for (int p = 0; p < 16; ++p) s += p4[(ip * 16 + p) * (BN / 4) + i4];
  ((f32x4*)part2)[ip * (BN / 4) + i4] = s;
}

// reduction stage 2 + squash (exact reference formula)
__global__ __launch_bounds__(256) void rs2_kernel(const float* __restrict__ part2,
                                                  float* __restrict__ o) {
  const int i4 = blockIdx.x * 256 + threadIdx.x;
  const f32x4* p4 = (const f32x4*)part2;
  f32x4 s = (f32x4){0.f, 0.f, 0.f, 0.f};
#pragma unroll
  for (int ip = 0; ip < 8; ++ip) s += p4[ip * (BN / 4) + i4];
  f32x4 r;
#pragma unroll
  for (int c = 0; c < 4; ++c) {
    const float sv = s[c];
    const float sq = sv * sv;
    r[c] = sq * sv / ((1.0f + sq) * sqrtf(sq));
  }
  ((f32x4*)o)[i4] = r;
}

// a-pass: bb[c][r] (+)= (1/64) * sum_{b,o} u_hat[b,r,c,o] * v[b,c,o]
// Block (rx,g) exclusively owns bb[g*4..g*4+4][r0..r0+RPB] -> no atomics.
template<bool FAST, bool FIRST>
__global__ __launch_bounds__(256, 4) void a_kernel(
    const float* __restrict__ x, const float* __restrict__ W,
    const unsigned short* __restrict__ xb, const unsigned short* __restrict__ Wb,
    const float* __restrict__ v,    // [B_][NCO]
    float* __restrict__ bb) {       // [C][R]
  const int tid  = threadIdx.x;
  const int lane = tid & 63;
  const int mw   = tid >> 6;
  const int g    = blockIdx.y;
  const int r0   = blockIdx.x * RPB;
  const int l15  = lane & 15;
  const int q    = lane >> 4;
  const int k0   = q * 8;
  const int bA   = mw * 16 + l15;

  // pairs per chunk: 4 capsules x 8 routes = 32; 2 chunks cover 16 routes
  __shared__ float slab[4][32][65];     // 33.3 KB
  __shared__ float accw[2][4][64];      // 2 KB

  // preload v in exact MFMA C-layout
  float vreg[8][4];
#pragma unroll
  for (int t = 0; t < 8; ++t) {
    const int n = g * NSL + t * 16 + l15;
#pragma unroll
    for (int rr = 0; rr < 4; ++rr)
      vreg[t][rr] = v[(mw * 16 + q * 4 + rr) * NCO + n];
  }
  const f32x4 zero4 = (f32x4){0.f, 0.f, 0.f, 0.f};

  for (int kk = 0; kk < 2; ++kk) {        // 2 chunks of 8 routes
    for (int jj = 0; jj < 8; ++jj) {
      const int r = r0 + kk * 8 + jj;
      bf16x8 af;
      if (FAST) {
        af = *(const bf16x8*)(xb + ((bA * R_ + r) * CI + k0));
      } else {
        const f32x4* xp = (const f32x4*)(x + ((bA * R_ + r) * CI + k0));
        af = pack8(xp[0], xp[1]);
      }
      bf16x8 wf[8];
#pragma unroll
      for (int t = 0; t < 8; ++t) {
        const int nrow = g * NSL + t * 16 + l15;
        const int wof = (r * NCO + nrow) * CI + k0;
        if (FAST) wf[t] = *(const bf16x8*)(Wb + wof);
        else {
          const f32x4* wp = (const f32x4*)(W + wof);
          wf[t] = pack8(wp[0], wp[1]);
        }
      }
      float dotc[4] = {0.f, 0.f, 0.f, 0.f};
#pragma unroll
      for (int t = 0; t < 8; ++t) {
        f32x4 u = __builtin_amdgcn_mfma_f32_16x16x32_bf16(af, wf[t], zero4, 0, 0, 0);
        dotc[t >> 1] += u[0] * vreg[t][0] + u[1] * vreg[t][1] +
                        u[2] * vreg[t][2] + u[3] * vreg[t][3];
      }
      // stash: pair p = cc*8 + jj ; stride-1 in lane -> conflict-free
#pragma unroll
      for (int cc = 0; cc < 4; ++cc)
        slab[mw][cc * 8 + jj][lane] = dotc[cc];
    }
    // half-reduction: lane -> pair p=lane>>1, half h=lane&1 (32 each)
    {
      const int p = lane >> 1, h = lane & 1;
      float sm = 0.f;
#pragma unroll
      for (int i = 0; i < 32; ++i) sm += slab[mw][p][h * 32 + i];
      accw[kk][mw][lane] = sm;
    }
  }
  __syncthreads();
  // final: 64 threads = 2 chunks x 32 pairs
  if (tid < 64) {
    const int kk = tid >> 5;
    const int p  = tid & 31;
    float tot = 0.f;
#pragma unroll
    for (int w = 0; w < 4; ++w)
      tot += accw[kk][w][p * 2] + accw[kk][w][p * 2 + 1];
    const int cc = p >> 3, jj = p & 7;
    const int r  = r0 + kk * 8 + jj;
    const int o  = (g * 4 + cc) * R_ + r;
    const float val = tot * (1.0f / 64.0f);
    bb[o] = FIRST ? val : (bb[o] + val);
  }
}

// softmax over routes for each capsule: cmat[c][r] = softmax_r(bb[c][r])
__global__ __launch_bounds__(256) void softmax_kernel(const float* __restrict__ bb,
                                                      float* __restrict__ cmat) {
  const int c = blockIdx.x;
  const int tid = threadIdx.x;
  __shared__ float red[8];
  float m = -1e30f;
  for (int r = tid; r < R_; r += 256) m = fmaxf(m, bb[c * R_ + r]);
#pragma unroll
  for (int s = 1; s < 64; s <<= 1) m = fmaxf(m, __shfl_xor(m, s));
  if ((tid & 63) == 0) red[tid >> 6] = m;
  __syncthreads();
  m = fmaxf(fmaxf(red[0], red[1]), fmaxf(red[2], red[3]));
  float sum = 0.f;
  for (int r = tid; r < R_; r += 256) sum += __expf(bb[c * R_ + r] - m);
#pragma unroll
  for (int s = 1; s < 64; s <<= 1) sum += __shfl_xor(sum, s);
  if ((tid & 63) == 0) red[4 + (tid >> 6)] = sum;
  __syncthreads();
  sum = red[4] + red[5] + red[6] + red[7];
  const float inv = 1.0f / sum;
  for (int r = tid; r < R_; r += 256)
    cmat[c * R_ + r] = __expf(bb[c * R_ + r] - m) * inv;
}

extern "C" void kernel_launch(void* const* d_in, const int* in_sizes, int n_in,
                              void* d_out, int out_size, void* d_ws, size_t ws_size,
                              hipStream_t stream) {
  const float* x = (const float*)d_in[0];   // [64, 2048, 32]
  const float* W = (const float*)d_in[1];   // [2048, 32, 32, 32]
  float* out = (float*)d_out;               // [64, 32, 32, 1]

  char* ws = (char*)d_ws;
  float* bb    = (float*)(ws);                          // 256 KB
  float* cmat  = (float*)(ws + (1 << 18));              // 256 KB
  float* vbuf  = (float*)(ws + 2 * (size_t)(1 << 18));  // 256 KB
  float* part2 = (float*)(ws + (1 << 20));              // 2 MB
  float* part  = (float*)(ws + 4 * (size_t)(1 << 20));  // 32 MB
  unsigned short* Wb = (unsigned short*)(ws + 36 * (size_t)(1 << 20));           // 128 MB
  unsigned short* xb = (unsigned short*)(ws + 36 * (size_t)(1 << 20) + WN * 2);  // 8 MB
  const size_t need_fast = 36 * (size_t)(1 << 20) + (size_t)WN * 2 + (size_t)XN * 2;
  const bool fast = ws_size >= need_fast;

  const dim3 grid(GR, NG);     // (128, 8)
  const dim3 rgrid(BN / 1024, 8);   // (64, 8)

  if (fast) {
    cvt_kernel<<<1024, 256, 0, stream>>>(x, xb, (int)(XN / 4));
    cvtW_kernel<<<2048, 256, 0, stream>>>(W, Wb);
    s_kernel<true, true><<<grid, 256, 0, stream>>>(x, W, xb, Wb, nullptr, part);
  } else {
    s_kernel<false, true><<<grid, 256, 0, stream>>>(x, W, xb, Wb, nullptr, part);
  }
  rs1_kernel<<<rgrid, 256, 0, stream>>>(part, part2);
  rs2_kernel<<<BN / 1024, 256, 0, stream>>>(part2, vbuf);

  if (fast) a_kernel<true, true><<<grid, 256, 0, stream>>>(x, W, xb, Wb, vbuf, bb);
  else      a_kernel<false, true><<<grid, 256, 0, stream>>>(x, W, xb, Wb, vbuf, bb);
  softmax_kernel<<<NC, 256, 0, stream>>>(bb, cmat);
  if (fast) s_kernel<true, false><<<grid, 256, 0, stream>>>(x, W, xb, Wb, cmat, part);
  else      s_kernel<false, false><<<grid, 256, 0, stream>>>(x, W, xb, Wb, cmat, part);
  rs1_kernel<<<rgrid, 256, 0, stream>>>(part, part2);
  rs2_kernel<<<BN / 1024, 256, 0, stream>>>(part2, vbuf);

  if (fast) a_kernel<true, false><<<grid, 256, 0, stream>>>(x, W, xb, Wb, vbuf, bb);
  else      a_kernel<false, false><<<grid, 256, 0, stream>>>(x, W, xb, Wb, vbuf, bb);
  softmax_kernel<<<NC, 256, 0, stream>>>(bb, cmat);
  if (fast) s_kernel<true, false><<<grid, 256, 0, stream>>>(x, W, xb, Wb, cmat, part);
  else      s_kernel<false, false><<<grid, 256, 0, stream>>>(x, W, xb, Wb, cmat, part);
  rs1_kernel<<<rgrid, 256, 0, stream>>>(part, part2);
  rs2_kernel<<<BN / 1024, 256, 0, stream>>>(part2, out);
}